// Round 2
// baseline (2173.453 us; speedup 1.0000x reference)
//
#include <hip/hip_runtime.h>
#include <math.h>
#include <stdint.h>

// EMACE forward, f32. Structure:
//  1) node_init: species argmax, h0 = W_embed[sp], e0 -> energy atomics
//  2) edge_count/scan/fill: receiver-grouped CSR of ACTIVE edges (r < 5) with
//     precomputed Y (16) and bessel feats (8), compacted
//  3) per layer: gather_update (wave per node): radial MLP per edge
//     (weights in LDS, transposed+padded), message accumulate into regs,
//     node update (inv, W_prod, W_sc), readout -> energy atomics
//  4) write_out

#define PI_F 3.14159265358979323846f

__device__ __forceinline__ float silu_f(float x) { return x / (1.f + __expf(-x)); }

// Wave-internal LDS fence: DS ops of a wave are processed in order; this
// waits for completion and stops compiler reordering/register-caching.
#define LDSFENCE() asm volatile("s_waitcnt lgkmcnt(0)" ::: "memory")

// ---------------------------------------------------------------- node init
__global__ void node_init_k(const float* __restrict__ attrs,
                            const float* __restrict__ ae,
                            const float* __restrict__ Wemb,
                            const int* __restrict__ batch,
                            float* __restrict__ h0, int* __restrict__ spec,
                            float* __restrict__ energy, int N, int NE) {
  int n = (int)((blockIdx.x * blockDim.x + threadIdx.x) >> 6);
  int lane = threadIdx.x & 63;
  if (n >= N) return;
  const float* a = attrs + (size_t)n * NE;
  int sp = 0;
  for (int e = 0; e < NE; ++e)
    if (a[e] > 0.5f) sp = e;
  h0[(size_t)n * 64 + lane] = Wemb[sp * 64 + lane];
  if (lane == 0) spec[n] = sp;
  if (lane < 3) atomicAdd(&energy[batch[n] * 3 + lane], ae[sp]);
}

// ---------------------------------------------------------------- edge pass 1
__global__ void edge_count_k(const float* __restrict__ pos,
                             const float* __restrict__ shifts,
                             const int* __restrict__ ei,
                             int* __restrict__ deg, int E) {
  int e = blockIdx.x * blockDim.x + threadIdx.x;
  if (e >= E) return;
  int s = ei[e], r = ei[E + e];
  float dx = pos[r * 3 + 0] - pos[s * 3 + 0] + shifts[e * 3 + 0];
  float dy = pos[r * 3 + 1] - pos[s * 3 + 1] + shifts[e * 3 + 1];
  float dz = pos[r * 3 + 2] - pos[s * 3 + 2] + shifts[e * 3 + 2];
  float rr = sqrtf(dx * dx + dy * dy + dz * dz + 1e-12f);
  if (rr < 5.0f) atomicAdd(&deg[r], 1);
}

// ---------------------------------------------------------------- scan
__global__ void scan_deg_k(const int* __restrict__ deg, int* __restrict__ off,
                           int N) {
  __shared__ int sdat[256];
  int tid = threadIdx.x;
  int chunk = (N + 255) / 256;
  int s0 = tid * chunk, s1 = min(s0 + chunk, N);
  int s = 0;
  for (int i = s0; i < s1; ++i) s += deg[i];
  sdat[tid] = s;
  __syncthreads();
  for (int d = 1; d < 256; d <<= 1) {
    int v = (tid >= d) ? sdat[tid - d] : 0;
    __syncthreads();
    sdat[tid] += v;
    __syncthreads();
  }
  int run = sdat[tid] - s;  // exclusive prefix
  for (int i = s0; i < s1; ++i) {
    off[i] = run;
    run += deg[i];
  }
  if (tid == 255) off[N] = sdat[255];
}

// ---------------------------------------------------------------- edge pass 2
__global__ void edge_fill_k(const float* __restrict__ pos,
                            const float* __restrict__ shifts,
                            const int* __restrict__ ei,
                            const int* __restrict__ off, int* __restrict__ cur,
                            int* __restrict__ send, float* __restrict__ Yc,
                            float* __restrict__ fc, int E) {
  int e = blockIdx.x * blockDim.x + threadIdx.x;
  if (e >= E) return;
  int s = ei[e], r = ei[E + e];
  float dx = pos[r * 3 + 0] - pos[s * 3 + 0] + shifts[e * 3 + 0];
  float dy = pos[r * 3 + 1] - pos[s * 3 + 1] + shifts[e * 3 + 1];
  float dz = pos[r * 3 + 2] - pos[s * 3 + 2] + shifts[e * 3 + 2];
  float rr = sqrtf(dx * dx + dy * dy + dz * dz + 1e-12f);
  if (rr >= 5.0f) return;  // inactive edge: cutoff=0 -> R=0 -> msg=0
  int p = off[r] + atomicAdd(&cur[r], 1);
  send[p] = s;
  float ir = 1.f / rr;
  float x = dx * ir, y = dy * ir, z = dz * ir;
  const float s3 = 1.73205080757f, s5 = 2.23606797750f, s15 = 3.87298334621f;
  const float c70 = 2.09165006634f;   // sqrt(70)/4
  const float c105 = 10.2469507660f;  // sqrt(105)
  const float c42 = 1.62018517460f;   // sqrt(42)/4
  const float c7 = 1.32287565553f;    // sqrt(7)/2
  float* Yp = Yc + (size_t)p * 16;
  float xx = x * x, yy = y * y, zz = z * z;
  Yp[0] = 1.f;
  Yp[1] = s3 * x;
  Yp[2] = s3 * y;
  Yp[3] = s3 * z;
  Yp[4] = s15 * x * y;
  Yp[5] = s15 * y * z;
  Yp[6] = 0.5f * s5 * (3.f * zz - 1.f);
  Yp[7] = s15 * x * z;
  Yp[8] = 0.5f * s15 * (xx - yy);
  Yp[9] = c70 * y * (3.f * xx - yy);
  Yp[10] = c105 * x * y * z;
  Yp[11] = c42 * y * (5.f * zz - 1.f);
  Yp[12] = c7 * z * (5.f * zz - 3.f);
  Yp[13] = c42 * x * (5.f * zz - 1.f);
  Yp[14] = 0.5f * c105 * z * (xx - yy);
  Yp[15] = c70 * x * (xx - 3.f * yy);
  float xr = rr * 0.2f;
  float xr2 = xr * xr, xr4 = xr2 * xr2;
  float xr5 = xr4 * xr, xr6 = xr5 * xr, xr7 = xr6 * xr;
  float poly = 1.f - 21.f * xr5 + 35.f * xr6 - 15.f * xr7;
  float pref = 0.632455532034f /* sqrt(2/5) */ * ir * poly;
  float* fp = fc + (size_t)p * 8;
#pragma unroll
  for (int nb = 1; nb <= 8; ++nb) fp[nb - 1] = pref * sinf(PI_F * (float)nb * xr);
}

// ---------------------------------------------------------------- main layer
#define NW 8  // waves per block

__device__ __forceinline__ void mlp64(const float* __restrict__ sW,
                                      float (*st)[64], int lane, float out[4]) {
  float a0 = 0.f, a1 = 0.f, a2 = 0.f, a3 = 0.f;
#pragma unroll
  for (int k0 = 0; k0 < 64; k0 += 4) {
    float4 w = *(const float4*)&sW[lane * 68 + k0];
    float4 v0 = *(const float4*)&st[0][k0];
    float4 v1 = *(const float4*)&st[1][k0];
    float4 v2 = *(const float4*)&st[2][k0];
    float4 v3 = *(const float4*)&st[3][k0];
    a0 += v0.x * w.x + v0.y * w.y + v0.z * w.z + v0.w * w.w;
    a1 += v1.x * w.x + v1.y * w.y + v1.z * w.z + v1.w * w.w;
    a2 += v2.x * w.x + v2.y * w.y + v2.z * w.z + v2.w * w.w;
    a3 += v3.x * w.x + v3.y * w.y + v3.z * w.z + v3.w * w.w;
  }
  out[0] = a0; out[1] = a1; out[2] = a2; out[3] = a3;
}

__global__ __launch_bounds__(512, 1) void gather_update_k(
    const float* __restrict__ h_in, float* __restrict__ h_out,
    const float* __restrict__ Wr1, const float* __restrict__ Wr2,
    const float* __restrict__ Wr3, const float* __restrict__ Wr4,
    const float* __restrict__ Wsc, const float* __restrict__ Wp,
    const float* __restrict__ Wread, const float* __restrict__ Yc,
    const float* __restrict__ fc, const int* __restrict__ send,
    const int* __restrict__ off, const int* __restrict__ spec,
    const int* __restrict__ batch, float* __restrict__ energy, int N, int NE,
    int layer) {
  __shared__ __attribute__((aligned(16))) float sW1[8 * 64];    //  2 KB [k*64+c]
  __shared__ __attribute__((aligned(16))) float sW2[64 * 68];   // 17 KB transposed+padded [c][k]
  __shared__ __attribute__((aligned(16))) float sW3[64 * 68];   // 17 KB
  __shared__ __attribute__((aligned(16))) float sW4[256 * 68];  // 70 KB [col][k], col = l*64+c
  __shared__ __attribute__((aligned(16))) float sStage[NW][4][64];
  __shared__ __attribute__((aligned(16))) float sVec[NW][64];

  int tid = threadIdx.x;
  {
    const float* w1 = Wr1 + (size_t)layer * 8 * 64;
    const float* w2 = Wr2 + (size_t)layer * 64 * 64;
    const float* w3 = Wr3 + (size_t)layer * 64 * 64;
    const float* w4 = Wr4 + (size_t)layer * 64 * 256;
    for (int i = tid; i < 8 * 64; i += 512) sW1[i] = w1[i];
    for (int i = tid; i < 64 * 64; i += 512) {
      int k = i >> 6, c = i & 63;
      sW2[c * 68 + k] = w2[i];
      sW3[c * 68 + k] = w3[i];
    }
    for (int i = tid; i < 64 * 256; i += 512) {
      int k = i >> 8, c = i & 255;
      sW4[c * 68 + k] = w4[i];
    }
  }
  __syncthreads();

  int wid = tid >> 6, lane = tid & 63;
  int n = blockIdx.x * NW + wid;
  if (n >= N) return;

  float (*st)[64] = sStage[wid];
  float* sv = sVec[wid];

  int base = off[n];
  int deg = off[n + 1] - base;
  float acc[16];
#pragma unroll
  for (int i = 0; i < 16; ++i) acc[i] = 0.f;

  for (int b = 0; b < deg; b += 4) {
    int m = min(4, deg - b);
    if (lane < 32) {
      int j = lane >> 3, k = lane & 7;
      st[j][k] = (j < m) ? fc[(size_t)(base + b + j) * 8 + k] : 0.f;
    }
    LDSFENCE();
    // L1: 8 -> 64, silu
    float h1[4];
    {
      float a0 = 0.f, a1 = 0.f, a2 = 0.f, a3 = 0.f;
#pragma unroll
      for (int k = 0; k < 8; ++k) {
        float w = sW1[k * 64 + lane];
        a0 += st[0][k] * w; a1 += st[1][k] * w;
        a2 += st[2][k] * w; a3 += st[3][k] * w;
      }
      h1[0] = a0; h1[1] = a1; h1[2] = a2; h1[3] = a3;
    }
    LDSFENCE();
    st[0][lane] = silu_f(h1[0]); st[1][lane] = silu_f(h1[1]);
    st[2][lane] = silu_f(h1[2]); st[3][lane] = silu_f(h1[3]);
    LDSFENCE();
    // L2
    float h2[4];
    mlp64(sW2, st, lane, h2);
    LDSFENCE();
    st[0][lane] = silu_f(h2[0]); st[1][lane] = silu_f(h2[1]);
    st[2][lane] = silu_f(h2[2]); st[3][lane] = silu_f(h2[3]);
    LDSFENCE();
    // L3
    float h3[4];
    mlp64(sW3, st, lane, h3);
    LDSFENCE();
    st[0][lane] = silu_f(h3[0]); st[1][lane] = silu_f(h3[1]);
    st[2][lane] = silu_f(h3[2]); st[3][lane] = silu_f(h3[3]);
    LDSFENCE();
    // L4: 64 -> 256 (no activation); R[j][l] = R_edge[l*64+lane]
    float R[4][4];
#pragma unroll
    for (int j = 0; j < 4; ++j)
#pragma unroll
      for (int l = 0; l < 4; ++l) R[j][l] = 0.f;
#pragma unroll
    for (int k0 = 0; k0 < 64; k0 += 4) {
      float4 v0 = *(const float4*)&st[0][k0];
      float4 v1 = *(const float4*)&st[1][k0];
      float4 v2 = *(const float4*)&st[2][k0];
      float4 v3 = *(const float4*)&st[3][k0];
#pragma unroll
      for (int l = 0; l < 4; ++l) {
        float4 w = *(const float4*)&sW4[(size_t)(l * 64 + lane) * 68 + k0];
        R[0][l] += v0.x * w.x + v0.y * w.y + v0.z * w.z + v0.w * w.w;
        R[1][l] += v1.x * w.x + v1.y * w.y + v1.z * w.z + v1.w * w.w;
        R[2][l] += v2.x * w.x + v2.y * w.y + v2.z * w.z + v2.w * w.w;
        R[3][l] += v3.x * w.x + v3.y * w.y + v3.z * w.z + v3.w * w.w;
      }
    }
    LDSFENCE();
    // accumulate messages: acc[lm] += Y[lm] * h_src[lane] * R[l_of_lm]
#pragma unroll
    for (int j = 0; j < 4; ++j) {
      if (j < m) {
        int e = base + b + j;
        float hs = h_in[(size_t)send[e] * 64 + lane];
        const float* Yp = Yc + (size_t)e * 16;
        float t0 = hs * R[j][0], t1 = hs * R[j][1];
        float t2 = hs * R[j][2], t3 = hs * R[j][3];
        acc[0] += Yp[0] * t0;
        acc[1] += Yp[1] * t1;  acc[2] += Yp[2] * t1;  acc[3] += Yp[3] * t1;
        acc[4] += Yp[4] * t2;  acc[5] += Yp[5] * t2;  acc[6] += Yp[6] * t2;
        acc[7] += Yp[7] * t2;  acc[8] += Yp[8] * t2;
        acc[9] += Yp[9] * t3;  acc[10] += Yp[10] * t3; acc[11] += Yp[11] * t3;
        acc[12] += Yp[12] * t3; acc[13] += Yp[13] * t3; acc[14] += Yp[14] * t3;
        acc[15] += Yp[15] * t3;
      }
    }
  }

  // node update: inv = A0 + sum_lm A^2   (A = acc / 16)
  float inv = acc[0] * 0.0625f;
#pragma unroll
  for (int i = 0; i < 16; ++i) {
    float a = acc[i] * 0.0625f;
    inv += a * a;
  }
  sv[lane] = inv;
  LDSFENCE();
  int sp = spec[n];
  const float* wsc = Wsc + ((size_t)layer * NE + sp) * 64 * 64;
  const float* wp = Wp + (size_t)layer * 64 * 64;
  const float* hold = h_in + (size_t)n * 64;
  float hv = 0.f;
#pragma unroll 4
  for (int k = 0; k < 64; ++k) {
    hv += sv[k] * wp[k * 64 + lane];
    hv += hold[k] * wsc[k * 64 + lane];
  }
  h_out[(size_t)n * 64 + lane] = hv;
  LDSFENCE();
  sv[lane] = hv;
  LDSFENCE();
  if (lane < 3) {
    const float* wr = Wread + (size_t)layer * 64 * 3;
    float s = 0.f;
#pragma unroll 8
    for (int d = 0; d < 64; ++d) s += sv[d] * wr[d * 3 + lane];
    atomicAdd(&energy[batch[n] * 3 + lane], s);
  }
}

// ---------------------------------------------------------------- output
__global__ void write_out_k(const float* __restrict__ energy,
                            float* __restrict__ out, int n) {
  int i = threadIdx.x;
  if (i < n) out[i] = energy[i];
}

// ---------------------------------------------------------------- host
extern "C" void kernel_launch(void* const* d_in, const int* in_sizes, int n_in,
                              void* d_out, int out_size, void* d_ws,
                              size_t ws_size, hipStream_t stream) {
  const float* pos = (const float*)d_in[0];
  const float* shifts = (const float*)d_in[1];
  const float* attrs = (const float*)d_in[2];
  const float* ae = (const float*)d_in[3];
  const float* Wemb = (const float*)d_in[4];
  const float* Wr1 = (const float*)d_in[5];
  const float* Wr2 = (const float*)d_in[6];
  const float* Wr3 = (const float*)d_in[7];
  const float* Wr4 = (const float*)d_in[8];
  const float* Wsc = (const float*)d_in[9];
  const float* Wp = (const float*)d_in[10];
  const float* Wrd = (const float*)d_in[11];
  const int* ei = (const int*)d_in[12];
  const int* batch = (const int*)d_in[13];

  int N = in_sizes[0] / 3;
  int E = in_sizes[12] / 2;
  int NE = in_sizes[3];
  int nlayer = in_sizes[5] / (8 * 64);

  char* w = (char*)d_ws;
  auto alloc = [&](size_t bytes) {
    void* p = (void*)w;
    w += (bytes + 255) & ~(size_t)255;
    return p;
  };
  float* h0 = (float*)alloc((size_t)N * 64 * 4);
  float* h1 = (float*)alloc((size_t)N * 64 * 4);
  float* Yc = (float*)alloc((size_t)E * 16 * 4);
  float* fc = (float*)alloc((size_t)E * 8 * 4);
  int* send = (int*)alloc((size_t)E * 4);
  int* off = (int*)alloc((size_t)(N + 1) * 4);
  int* deg = (int*)alloc((size_t)N * 4);
  int* cur = (int*)alloc((size_t)N * 4);
  int* spec = (int*)alloc((size_t)N * 4);
  float* energy = (float*)alloc(64 * 4);

  hipMemsetAsync(deg, 0, (size_t)N * 4, stream);
  hipMemsetAsync(cur, 0, (size_t)N * 4, stream);
  hipMemsetAsync(energy, 0, 64 * 4, stream);

  node_init_k<<<(N + 3) / 4, 256, 0, stream>>>(attrs, ae, Wemb, batch, h0, spec,
                                               energy, N, NE);
  edge_count_k<<<(E + 255) / 256, 256, 0, stream>>>(pos, shifts, ei, deg, E);
  scan_deg_k<<<1, 256, 0, stream>>>(deg, off, N);
  edge_fill_k<<<(E + 255) / 256, 256, 0, stream>>>(pos, shifts, ei, off, cur,
                                                   send, Yc, fc, E);
  float* hin = h0;
  float* hout = h1;
  for (int l = 0; l < nlayer; ++l) {
    gather_update_k<<<(N + NW - 1) / NW, 512, 0, stream>>>(
        hin, hout, Wr1, Wr2, Wr3, Wr4, Wsc, Wp, Wrd, Yc, fc, send, off, spec,
        batch, energy, N, NE, l);
    float* t = hin; hin = hout; hout = t;
  }
  write_out_k<<<1, 64, 0, stream>>>(energy, (float*)d_out, out_size);
}

// Round 3
// 501.978 us; speedup vs baseline: 4.3298x; 4.3298x over previous
//
#include <hip/hip_runtime.h>
#include <math.h>
#include <stdint.h>

// EMACE forward, f32.
// R3 change vs R2: gather_update inner loop rebuilt to kill VGPR-spill
// scratch traffic (2.9 GB/dispatch observed): 2-edge batches, partial
// unroll, bounded live ranges, hs-gather prefetch, k0 rotation for
// conflict-free stride-68 LDS reads.

#define PI_F 3.14159265358979323846f

__device__ __forceinline__ float silu_f(float x) { return x / (1.f + __expf(-x)); }

// Wave-internal LDS fence: DS ops of a wave complete in order; wait + stop
// compiler reordering/register-caching across it.
#define LDSFENCE() asm volatile("s_waitcnt lgkmcnt(0)" ::: "memory")

// ---------------------------------------------------------------- node init
__global__ void node_init_k(const float* __restrict__ attrs,
                            const float* __restrict__ ae,
                            const float* __restrict__ Wemb,
                            const int* __restrict__ batch,
                            float* __restrict__ h0, int* __restrict__ spec,
                            float* __restrict__ energy, int N, int NE) {
  int n = (int)((blockIdx.x * blockDim.x + threadIdx.x) >> 6);
  int lane = threadIdx.x & 63;
  if (n >= N) return;
  const float* a = attrs + (size_t)n * NE;
  int sp = 0;
  for (int e = 0; e < NE; ++e)
    if (a[e] > 0.5f) sp = e;
  h0[(size_t)n * 64 + lane] = Wemb[sp * 64 + lane];
  if (lane == 0) spec[n] = sp;
  if (lane < 3) atomicAdd(&energy[batch[n] * 3 + lane], ae[sp]);
}

// ---------------------------------------------------------------- edge pass 1
__global__ void edge_count_k(const float* __restrict__ pos,
                             const float* __restrict__ shifts,
                             const int* __restrict__ ei,
                             int* __restrict__ deg, int E) {
  int e = blockIdx.x * blockDim.x + threadIdx.x;
  if (e >= E) return;
  int s = ei[e], r = ei[E + e];
  float dx = pos[r * 3 + 0] - pos[s * 3 + 0] + shifts[e * 3 + 0];
  float dy = pos[r * 3 + 1] - pos[s * 3 + 1] + shifts[e * 3 + 1];
  float dz = pos[r * 3 + 2] - pos[s * 3 + 2] + shifts[e * 3 + 2];
  float rr = sqrtf(dx * dx + dy * dy + dz * dz + 1e-12f);
  if (rr < 5.0f) atomicAdd(&deg[r], 1);
}

// ---------------------------------------------------------------- scan
__global__ void scan_deg_k(const int* __restrict__ deg, int* __restrict__ off,
                           int N) {
  __shared__ int sdat[256];
  int tid = threadIdx.x;
  int chunk = (N + 255) / 256;
  int s0 = tid * chunk, s1 = min(s0 + chunk, N);
  int s = 0;
  for (int i = s0; i < s1; ++i) s += deg[i];
  sdat[tid] = s;
  __syncthreads();
  for (int d = 1; d < 256; d <<= 1) {
    int v = (tid >= d) ? sdat[tid - d] : 0;
    __syncthreads();
    sdat[tid] += v;
    __syncthreads();
  }
  int run = sdat[tid] - s;  // exclusive prefix
  for (int i = s0; i < s1; ++i) {
    off[i] = run;
    run += deg[i];
  }
  if (tid == 255) off[N] = sdat[255];
}

// ---------------------------------------------------------------- edge pass 2
__global__ void edge_fill_k(const float* __restrict__ pos,
                            const float* __restrict__ shifts,
                            const int* __restrict__ ei,
                            const int* __restrict__ off, int* __restrict__ cur,
                            int* __restrict__ send, float* __restrict__ Yc,
                            float* __restrict__ fc, int E) {
  int e = blockIdx.x * blockDim.x + threadIdx.x;
  if (e >= E) return;
  int s = ei[e], r = ei[E + e];
  float dx = pos[r * 3 + 0] - pos[s * 3 + 0] + shifts[e * 3 + 0];
  float dy = pos[r * 3 + 1] - pos[s * 3 + 1] + shifts[e * 3 + 1];
  float dz = pos[r * 3 + 2] - pos[s * 3 + 2] + shifts[e * 3 + 2];
  float rr = sqrtf(dx * dx + dy * dy + dz * dz + 1e-12f);
  if (rr >= 5.0f) return;  // inactive edge: cutoff=0 -> R=0 -> msg=0
  int p = off[r] + atomicAdd(&cur[r], 1);
  send[p] = s;
  float ir = 1.f / rr;
  float x = dx * ir, y = dy * ir, z = dz * ir;
  const float s3 = 1.73205080757f, s5 = 2.23606797750f, s15 = 3.87298334621f;
  const float c70 = 2.09165006634f;   // sqrt(70)/4
  const float c105 = 10.2469507660f;  // sqrt(105)
  const float c42 = 1.62018517460f;   // sqrt(42)/4
  const float c7 = 1.32287565553f;    // sqrt(7)/2
  float* Yp = Yc + (size_t)p * 16;
  float xx = x * x, yy = y * y, zz = z * z;
  Yp[0] = 1.f;
  Yp[1] = s3 * x;
  Yp[2] = s3 * y;
  Yp[3] = s3 * z;
  Yp[4] = s15 * x * y;
  Yp[5] = s15 * y * z;
  Yp[6] = 0.5f * s5 * (3.f * zz - 1.f);
  Yp[7] = s15 * x * z;
  Yp[8] = 0.5f * s15 * (xx - yy);
  Yp[9] = c70 * y * (3.f * xx - yy);
  Yp[10] = c105 * x * y * z;
  Yp[11] = c42 * y * (5.f * zz - 1.f);
  Yp[12] = c7 * z * (5.f * zz - 3.f);
  Yp[13] = c42 * x * (5.f * zz - 1.f);
  Yp[14] = 0.5f * c105 * z * (xx - yy);
  Yp[15] = c70 * x * (xx - 3.f * yy);
  float xr = rr * 0.2f;
  float xr2 = xr * xr, xr4 = xr2 * xr2;
  float xr5 = xr4 * xr, xr6 = xr5 * xr, xr7 = xr6 * xr;
  float poly = 1.f - 21.f * xr5 + 35.f * xr6 - 15.f * xr7;
  float pref = 0.632455532034f /* sqrt(2/5) */ * ir * poly;
  float* fp = fc + (size_t)p * 8;
#pragma unroll
  for (int nb = 1; nb <= 8; ++nb) fp[nb - 1] = pref * sinf(PI_F * (float)nb * xr);
}

// ---------------------------------------------------------------- main layer
#define NW 8  // waves per block

// 64->64 layer for 2 edges; stride-68 rows, k0 start rotated per lane so the
// 8-lane same-bank sets (lanes == mod 8; 544B == 0 mod 32 banks) spread out.
__device__ __forceinline__ void mlp2(const float* __restrict__ sW,
                                     float (*st)[64], int lane, int rot,
                                     float out[2]) {
  float a0 = 0.f, a1 = 0.f;
#pragma unroll 4
  for (int i = 0; i < 16; ++i) {
    int t = (i + rot) & 15;
    float4 w = *(const float4*)&sW[lane * 68 + 4 * t];
    float4 v0 = *(const float4*)&st[0][4 * t];
    float4 v1 = *(const float4*)&st[1][4 * t];
    a0 += v0.x * w.x + v0.y * w.y + v0.z * w.z + v0.w * w.w;
    a1 += v1.x * w.x + v1.y * w.y + v1.z * w.z + v1.w * w.w;
  }
  out[0] = a0;
  out[1] = a1;
}

__global__ __launch_bounds__(512, 1) void gather_update_k(
    const float* __restrict__ h_in, float* __restrict__ h_out,
    const float* __restrict__ Wr1, const float* __restrict__ Wr2,
    const float* __restrict__ Wr3, const float* __restrict__ Wr4,
    const float* __restrict__ Wsc, const float* __restrict__ Wp,
    const float* __restrict__ Wread, const float* __restrict__ Yc,
    const float* __restrict__ fc, const int* __restrict__ send,
    const int* __restrict__ off, const int* __restrict__ spec,
    const int* __restrict__ batch, float* __restrict__ energy, int N, int NE,
    int layer) {
  __shared__ __attribute__((aligned(16))) float sW1[8 * 64];    //  2 KB [k*64+c]
  __shared__ __attribute__((aligned(16))) float sW2[64 * 68];   // 17 KB [c][k] pad68
  __shared__ __attribute__((aligned(16))) float sW3[64 * 68];   // 17 KB
  __shared__ __attribute__((aligned(16))) float sW4[256 * 68];  // 70 KB [l*64+c][k]
  __shared__ __attribute__((aligned(16))) float sStage[NW][2][64];
  __shared__ __attribute__((aligned(16))) float sVec[NW][64];

  int tid = threadIdx.x;
  {
    const float* w1 = Wr1 + (size_t)layer * 8 * 64;
    const float* w2 = Wr2 + (size_t)layer * 64 * 64;
    const float* w3 = Wr3 + (size_t)layer * 64 * 64;
    const float* w4 = Wr4 + (size_t)layer * 64 * 256;
    for (int i = tid; i < 8 * 64; i += 512) sW1[i] = w1[i];
    for (int i = tid; i < 64 * 64; i += 512) {
      int k = i >> 6, c = i & 63;
      sW2[c * 68 + k] = w2[i];
      sW3[c * 68 + k] = w3[i];
    }
    for (int i = tid; i < 64 * 256; i += 512) {
      int k = i >> 8, c = i & 255;
      sW4[c * 68 + k] = w4[i];
    }
  }
  __syncthreads();

  int wid = tid >> 6, lane = tid & 63;
  int n = blockIdx.x * NW + wid;
  if (n >= N) return;

  float (*st)[64] = sStage[wid];
  float* sv = sVec[wid];
  int rot = lane >> 3;  // 0..7

  int base = off[n];
  int deg = off[n + 1] - base;
  float acc[16];
#pragma unroll
  for (int i = 0; i < 16; ++i) acc[i] = 0.f;

  for (int b = 0; b < deg; b += 2) {
    int m = min(2, deg - b);
    int e0 = base + b;
    int e1 = e0 + (m - 1);  // ==e0 when m==1 (avoid reading unfilled send[])
    int s0 = send[e0], s1 = send[e1];
    // prefetch gathers; resolved during the MLP below
    float hs0 = h_in[(size_t)s0 * 64 + lane];
    float hs1 = h_in[(size_t)s1 * 64 + lane];
    if (lane < 16) {
      int j = lane >> 3, k = lane & 7;
      st[j][k] = (j < m) ? fc[(size_t)(e0 + j) * 8 + k] : 0.f;
    }
    LDSFENCE();
    // L1: 8 -> 64, silu
    float a0 = 0.f, a1 = 0.f;
#pragma unroll
    for (int k = 0; k < 8; ++k) {
      float w = sW1[k * 64 + lane];
      a0 += st[0][k] * w;
      a1 += st[1][k] * w;
    }
    LDSFENCE();
    st[0][lane] = silu_f(a0);
    st[1][lane] = silu_f(a1);
    LDSFENCE();
    // L2
    float h2[2];
    mlp2(sW2, st, lane, rot, h2);
    LDSFENCE();
    st[0][lane] = silu_f(h2[0]);
    st[1][lane] = silu_f(h2[1]);
    LDSFENCE();
    // L3
    float h3[2];
    mlp2(sW3, st, lane, rot, h3);
    LDSFENCE();
    st[0][lane] = silu_f(h3[0]);
    st[1][lane] = silu_f(h3[1]);
    LDSFENCE();
    // L4: 64 -> 256, R[l] = R_edge[l*64+lane]; i-outer, l-inner keeps live
    // state bounded (v0,v1 + one w in flight + 8 accumulators).
    float R0[4] = {0.f, 0.f, 0.f, 0.f};
    float R1[4] = {0.f, 0.f, 0.f, 0.f};
#pragma unroll 2
    for (int i = 0; i < 16; ++i) {
      int t = (i + rot) & 15;
      float4 v0 = *(const float4*)&st[0][4 * t];
      float4 v1 = *(const float4*)&st[1][4 * t];
#pragma unroll
      for (int l = 0; l < 4; ++l) {
        float4 w = *(const float4*)&sW4[(size_t)(l * 64 + lane) * 68 + 4 * t];
        R0[l] += v0.x * w.x + v0.y * w.y + v0.z * w.z + v0.w * w.w;
        R1[l] += v1.x * w.x + v1.y * w.y + v1.z * w.z + v1.w * w.w;
      }
    }
    LDSFENCE();
    // accumulate messages: acc[lm] += Y[lm] * h_src[lane] * R[l_of_lm]
#pragma unroll
    for (int j = 0; j < 2; ++j) {
      if (j < m) {
        float hs = j ? hs1 : hs0;
        const float* Rj = j ? R1 : R0;
        const float* Yp = Yc + (size_t)(e0 + j) * 16;
        float t0 = hs * Rj[0], t1 = hs * Rj[1];
        float t2 = hs * Rj[2], t3 = hs * Rj[3];
        acc[0] += Yp[0] * t0;
        acc[1] += Yp[1] * t1;   acc[2] += Yp[2] * t1;   acc[3] += Yp[3] * t1;
        acc[4] += Yp[4] * t2;   acc[5] += Yp[5] * t2;   acc[6] += Yp[6] * t2;
        acc[7] += Yp[7] * t2;   acc[8] += Yp[8] * t2;
        acc[9] += Yp[9] * t3;   acc[10] += Yp[10] * t3; acc[11] += Yp[11] * t3;
        acc[12] += Yp[12] * t3; acc[13] += Yp[13] * t3; acc[14] += Yp[14] * t3;
        acc[15] += Yp[15] * t3;
      }
    }
  }

  // node update: inv = A0 + sum_lm A^2   (A = acc / 16)
  float inv = acc[0] * 0.0625f;
#pragma unroll
  for (int i = 0; i < 16; ++i) {
    float a = acc[i] * 0.0625f;
    inv += a * a;
  }
  sv[lane] = inv;
  LDSFENCE();
  int sp = spec[n];
  const float* wsc = Wsc + ((size_t)layer * NE + sp) * 64 * 64;
  const float* wp = Wp + (size_t)layer * 64 * 64;
  const float* hold = h_in + (size_t)n * 64;
  float hv = 0.f;
#pragma unroll 4
  for (int k = 0; k < 64; ++k) {
    hv += sv[k] * wp[k * 64 + lane];
    hv += hold[k] * wsc[k * 64 + lane];
  }
  h_out[(size_t)n * 64 + lane] = hv;
  LDSFENCE();
  sv[lane] = hv;
  LDSFENCE();
  if (lane < 3) {
    const float* wr = Wread + (size_t)layer * 64 * 3;
    float s = 0.f;
#pragma unroll 8
    for (int d = 0; d < 64; ++d) s += sv[d] * wr[d * 3 + lane];
    atomicAdd(&energy[batch[n] * 3 + lane], s);
  }
}

// ---------------------------------------------------------------- output
__global__ void write_out_k(const float* __restrict__ energy,
                            float* __restrict__ out, int n) {
  int i = threadIdx.x;
  if (i < n) out[i] = energy[i];
}

// ---------------------------------------------------------------- host
extern "C" void kernel_launch(void* const* d_in, const int* in_sizes, int n_in,
                              void* d_out, int out_size, void* d_ws,
                              size_t ws_size, hipStream_t stream) {
  const float* pos = (const float*)d_in[0];
  const float* shifts = (const float*)d_in[1];
  const float* attrs = (const float*)d_in[2];
  const float* ae = (const float*)d_in[3];
  const float* Wemb = (const float*)d_in[4];
  const float* Wr1 = (const float*)d_in[5];
  const float* Wr2 = (const float*)d_in[6];
  const float* Wr3 = (const float*)d_in[7];
  const float* Wr4 = (const float*)d_in[8];
  const float* Wsc = (const float*)d_in[9];
  const float* Wp = (const float*)d_in[10];
  const float* Wrd = (const float*)d_in[11];
  const int* ei = (const int*)d_in[12];
  const int* batch = (const int*)d_in[13];

  int N = in_sizes[0] / 3;
  int E = in_sizes[12] / 2;
  int NE = in_sizes[3];
  int nlayer = in_sizes[5] / (8 * 64);

  char* w = (char*)d_ws;
  auto alloc = [&](size_t bytes) {
    void* p = (void*)w;
    w += (bytes + 255) & ~(size_t)255;
    return p;
  };
  float* h0 = (float*)alloc((size_t)N * 64 * 4);
  float* h1 = (float*)alloc((size_t)N * 64 * 4);
  float* Yc = (float*)alloc((size_t)E * 16 * 4);
  float* fc = (float*)alloc((size_t)E * 8 * 4);
  int* send = (int*)alloc((size_t)E * 4);
  int* off = (int*)alloc((size_t)(N + 1) * 4);
  int* deg = (int*)alloc((size_t)N * 4);
  int* cur = (int*)alloc((size_t)N * 4);
  int* spec = (int*)alloc((size_t)N * 4);
  float* energy = (float*)alloc(64 * 4);

  hipMemsetAsync(deg, 0, (size_t)N * 4, stream);
  hipMemsetAsync(cur, 0, (size_t)N * 4, stream);
  hipMemsetAsync(energy, 0, 64 * 4, stream);

  node_init_k<<<(N + 3) / 4, 256, 0, stream>>>(attrs, ae, Wemb, batch, h0, spec,
                                               energy, N, NE);
  edge_count_k<<<(E + 255) / 256, 256, 0, stream>>>(pos, shifts, ei, deg, E);
  scan_deg_k<<<1, 256, 0, stream>>>(deg, off, N);
  edge_fill_k<<<(E + 255) / 256, 256, 0, stream>>>(pos, shifts, ei, off, cur,
                                                   send, Yc, fc, E);
  float* hin = h0;
  float* hout = h1;
  for (int l = 0; l < nlayer; ++l) {
    gather_update_k<<<(N + NW - 1) / NW, 512, 0, stream>>>(
        hin, hout, Wr1, Wr2, Wr3, Wr4, Wsc, Wp, Wrd, Yc, fc, send, off, spec,
        batch, energy, N, NE, l);
    float* t = hin;
    hin = hout;
    hout = t;
  }
  write_out_k<<<1, 64, 0, stream>>>(energy, (float*)d_out, out_size);
}

// Round 4
// 499.842 us; speedup vs baseline: 4.3483x; 1.0043x over previous
//
#include <hip/hip_runtime.h>
#include <math.h>
#include <stdint.h>

// EMACE forward, f32.
// R4 change vs R3: gather_update rebuilt around lane=channel broadcast-x MLP
// with 6-edge chunks per node: weight ds_read_b128 amortized 6x, activations
// read via wave-uniform LDS broadcasts, XOR quad-swizzle on weight storage
// for bank-conflict-free column reads.

#define PI_F 3.14159265358979323846f

__device__ __forceinline__ float silu_f(float x) { return x / (1.f + __expf(-x)); }

// Wave-internal LDS fence: DS ops of a wave complete in order; wait + stop
// compiler reordering/register-caching across it.
#define LDSFENCE() asm volatile("s_waitcnt lgkmcnt(0)" ::: "memory")

// ---------------------------------------------------------------- node init
__global__ void node_init_k(const float* __restrict__ attrs,
                            const float* __restrict__ ae,
                            const float* __restrict__ Wemb,
                            const int* __restrict__ batch,
                            float* __restrict__ h0, int* __restrict__ spec,
                            float* __restrict__ energy, int N, int NE) {
  int n = (int)((blockIdx.x * blockDim.x + threadIdx.x) >> 6);
  int lane = threadIdx.x & 63;
  if (n >= N) return;
  const float* a = attrs + (size_t)n * NE;
  int sp = 0;
  for (int e = 0; e < NE; ++e)
    if (a[e] > 0.5f) sp = e;
  h0[(size_t)n * 64 + lane] = Wemb[sp * 64 + lane];
  if (lane == 0) spec[n] = sp;
  if (lane < 3) atomicAdd(&energy[batch[n] * 3 + lane], ae[sp]);
}

// ---------------------------------------------------------------- edge pass 1
__global__ void edge_count_k(const float* __restrict__ pos,
                             const float* __restrict__ shifts,
                             const int* __restrict__ ei,
                             int* __restrict__ deg, int E) {
  int e = blockIdx.x * blockDim.x + threadIdx.x;
  if (e >= E) return;
  int s = ei[e], r = ei[E + e];
  float dx = pos[r * 3 + 0] - pos[s * 3 + 0] + shifts[e * 3 + 0];
  float dy = pos[r * 3 + 1] - pos[s * 3 + 1] + shifts[e * 3 + 1];
  float dz = pos[r * 3 + 2] - pos[s * 3 + 2] + shifts[e * 3 + 2];
  float rr = sqrtf(dx * dx + dy * dy + dz * dz + 1e-12f);
  if (rr < 5.0f) atomicAdd(&deg[r], 1);
}

// ---------------------------------------------------------------- scan
__global__ void scan_deg_k(const int* __restrict__ deg, int* __restrict__ off,
                           int N) {
  __shared__ int sdat[256];
  int tid = threadIdx.x;
  int chunk = (N + 255) / 256;
  int s0 = tid * chunk, s1 = min(s0 + chunk, N);
  int s = 0;
  for (int i = s0; i < s1; ++i) s += deg[i];
  sdat[tid] = s;
  __syncthreads();
  for (int d = 1; d < 256; d <<= 1) {
    int v = (tid >= d) ? sdat[tid - d] : 0;
    __syncthreads();
    sdat[tid] += v;
    __syncthreads();
  }
  int run = sdat[tid] - s;  // exclusive prefix
  for (int i = s0; i < s1; ++i) {
    off[i] = run;
    run += deg[i];
  }
  if (tid == 255) off[N] = sdat[255];
}

// ---------------------------------------------------------------- edge pass 2
__global__ void edge_fill_k(const float* __restrict__ pos,
                            const float* __restrict__ shifts,
                            const int* __restrict__ ei,
                            const int* __restrict__ off, int* __restrict__ cur,
                            int* __restrict__ send, float* __restrict__ Yc,
                            float* __restrict__ fc, int E) {
  int e = blockIdx.x * blockDim.x + threadIdx.x;
  if (e >= E) return;
  int s = ei[e], r = ei[E + e];
  float dx = pos[r * 3 + 0] - pos[s * 3 + 0] + shifts[e * 3 + 0];
  float dy = pos[r * 3 + 1] - pos[s * 3 + 1] + shifts[e * 3 + 1];
  float dz = pos[r * 3 + 2] - pos[s * 3 + 2] + shifts[e * 3 + 2];
  float rr = sqrtf(dx * dx + dy * dy + dz * dz + 1e-12f);
  if (rr >= 5.0f) return;  // inactive edge: cutoff=0 -> R=0 -> msg=0
  int p = off[r] + atomicAdd(&cur[r], 1);
  send[p] = s;
  float ir = 1.f / rr;
  float x = dx * ir, y = dy * ir, z = dz * ir;
  const float s3 = 1.73205080757f, s5 = 2.23606797750f, s15 = 3.87298334621f;
  const float c70 = 2.09165006634f;   // sqrt(70)/4
  const float c105 = 10.2469507660f;  // sqrt(105)
  const float c42 = 1.62018517460f;   // sqrt(42)/4
  const float c7 = 1.32287565553f;    // sqrt(7)/2
  float* Yp = Yc + (size_t)p * 16;
  float xx = x * x, yy = y * y, zz = z * z;
  Yp[0] = 1.f;
  Yp[1] = s3 * x;
  Yp[2] = s3 * y;
  Yp[3] = s3 * z;
  Yp[4] = s15 * x * y;
  Yp[5] = s15 * y * z;
  Yp[6] = 0.5f * s5 * (3.f * zz - 1.f);
  Yp[7] = s15 * x * z;
  Yp[8] = 0.5f * s15 * (xx - yy);
  Yp[9] = c70 * y * (3.f * xx - yy);
  Yp[10] = c105 * x * y * z;
  Yp[11] = c42 * y * (5.f * zz - 1.f);
  Yp[12] = c7 * z * (5.f * zz - 3.f);
  Yp[13] = c42 * x * (5.f * zz - 1.f);
  Yp[14] = 0.5f * c105 * z * (xx - yy);
  Yp[15] = c70 * x * (xx - 3.f * yy);
  float xr = rr * 0.2f;
  float xr2 = xr * xr, xr4 = xr2 * xr2;
  float xr5 = xr4 * xr, xr6 = xr5 * xr, xr7 = xr6 * xr;
  float poly = 1.f - 21.f * xr5 + 35.f * xr6 - 15.f * xr7;
  float pref = 0.632455532034f /* sqrt(2/5) */ * ir * poly;
  float* fp = fc + (size_t)p * 8;
#pragma unroll
  for (int nb = 1; nb <= 8; ++nb) fp[nb - 1] = pref * sinf(PI_F * (float)nb * xr);
}

// ---------------------------------------------------------------- main layer
#define NW 8   // waves per block
#define EB 6   // edges per chunk (covers avg deg 4.5 in one pass)

// One 64->64 layer for 6 edges: lane = output channel; weight column from
// LDS (stride 68, quad XOR-swizzled by q^(c>>3) for bank spread); activation
// quads are wave-uniform broadcasts.
#define MLP6(sWX, A)                                                       \
  {                                                                        \
    _Pragma("unroll") for (int j = 0; j < EB; ++j) A[j] = 0.f;             \
    _Pragma("unroll 4") for (int t = 0; t < 16; ++t) {                     \
      float4 w = *(const float4*)&sWX[lane * 68 + 4 * (t ^ rots)];         \
      _Pragma("unroll") for (int j = 0; j < EB; ++j) {                     \
        float4 x = *(const float4*)&st[j * 64 + 4 * t];                    \
        A[j] += x.x * w.x + x.y * w.y + x.z * w.z + x.w * w.w;             \
      }                                                                    \
    }                                                                      \
  }

__global__ __launch_bounds__(512, 1) void gather_update_k(
    const float* __restrict__ h_in, float* __restrict__ h_out,
    const float* __restrict__ Wr1, const float* __restrict__ Wr2,
    const float* __restrict__ Wr3, const float* __restrict__ Wr4,
    const float* __restrict__ Wsc, const float* __restrict__ Wp,
    const float* __restrict__ Wread, const float* __restrict__ Yc,
    const float* __restrict__ fc, const int* __restrict__ send,
    const int* __restrict__ off, const int* __restrict__ spec,
    const int* __restrict__ batch, float* __restrict__ energy, int N, int NE,
    int layer) {
  __shared__ __attribute__((aligned(16))) float sW1[8 * 64];    // [k*64+c]
  __shared__ __attribute__((aligned(16))) float sW2[64 * 68];   // [c][q^swz]
  __shared__ __attribute__((aligned(16))) float sW3[64 * 68];
  __shared__ __attribute__((aligned(16))) float sW4[256 * 68];  // [l*64+c][q^swz]
  __shared__ __attribute__((aligned(16))) float sStf[NW][48];   // fc stage
  __shared__ __attribute__((aligned(16))) float sSt[NW][EB * 64];  // activations
  __shared__ __attribute__((aligned(16))) float sSY[NW][96];    // Y stage
  __shared__ __attribute__((aligned(16))) float sVec[NW][64];

  int tid = threadIdx.x;
  {
    const float* w1 = Wr1 + (size_t)layer * 8 * 64;
    const float* w2 = Wr2 + (size_t)layer * 64 * 64;
    const float* w3 = Wr3 + (size_t)layer * 64 * 64;
    const float* w4 = Wr4 + (size_t)layer * 64 * 256;
    for (int i = tid; i < 8 * 64; i += 512) sW1[i] = w1[i];
    for (int i = tid; i < 64 * 64; i += 512) {
      int k = i >> 6, c = i & 63;
      int pos = c * 68 + 4 * ((k >> 2) ^ (c >> 3)) + (k & 3);
      sW2[pos] = w2[i];
      sW3[pos] = w3[i];
    }
    for (int i = tid; i < 64 * 256; i += 512) {
      int k = i >> 8, c = i & 255;
      int pos = c * 68 + 4 * ((k >> 2) ^ ((c >> 3) & 7)) + (k & 3);
      sW4[pos] = w4[i];
    }
  }
  __syncthreads();

  int wid = tid >> 6, lane = tid & 63;
  int n = blockIdx.x * NW + wid;
  if (n >= N) return;

  float* st = sSt[wid];
  float* stf = sStf[wid];
  float* sy = sSY[wid];
  float* sv = sVec[wid];
  int rots = lane >> 3;  // 0..7

  int base = off[n];
  int deg = off[n + 1] - base;
  float acc[16];
#pragma unroll
  for (int i = 0; i < 16; ++i) acc[i] = 0.f;

  for (int b = 0; b < deg; b += EB) {
    int m = min(EB, deg - b);
    // prefetch sender features (consumed at the very end of the chunk)
    float hs[EB];
#pragma unroll
    for (int j = 0; j < EB; ++j) {
      int e = base + b + (j < m ? j : m - 1);
      hs[j] = h_in[(size_t)send[e] * 64 + lane];
    }
    // stage fc (clamped-duplicate padding) and Y (real edges only)
    if (lane < 48) {
      int j = lane >> 3, k = lane & 7;
      int e = base + b + (j < m ? j : m - 1);
      stf[lane] = fc[(size_t)e * 8 + k];
    }
    {
      int nY = m * 16;
      const float* ysrc = Yc + (size_t)(base + b) * 16;
      if (lane < nY) sy[lane] = ysrc[lane];
      if (lane + 64 < nY) sy[lane + 64] = ysrc[lane + 64];
    }
    LDSFENCE();
    // L1: 8 -> 64
    float a[EB];
#pragma unroll
    for (int j = 0; j < EB; ++j) a[j] = 0.f;
#pragma unroll
    for (int k = 0; k < 8; ++k) {
      float w = sW1[k * 64 + lane];
#pragma unroll
      for (int j = 0; j < EB; ++j) a[j] += stf[j * 8 + k] * w;
    }
    LDSFENCE();
#pragma unroll
    for (int j = 0; j < EB; ++j) st[j * 64 + lane] = silu_f(a[j]);
    LDSFENCE();
    // L2
    MLP6(sW2, a);
    LDSFENCE();
#pragma unroll
    for (int j = 0; j < EB; ++j) st[j * 64 + lane] = silu_f(a[j]);
    LDSFENCE();
    // L3
    MLP6(sW3, a);
    LDSFENCE();
#pragma unroll
    for (int j = 0; j < EB; ++j) st[j * 64 + lane] = silu_f(a[j]);
    LDSFENCE();
    // L4: 64 -> 256; r4[j][l] = R_edge_j[l*64+lane]
    float r4[EB][4];
#pragma unroll
    for (int j = 0; j < EB; ++j)
#pragma unroll
      for (int l = 0; l < 4; ++l) r4[j][l] = 0.f;
#pragma unroll 1
    for (int t = 0; t < 16; ++t) {
      float4 xq[EB];
#pragma unroll
      for (int j = 0; j < EB; ++j) xq[j] = *(const float4*)&st[j * 64 + 4 * t];
#pragma unroll
      for (int l = 0; l < 4; ++l) {
        float4 w =
            *(const float4*)&sW4[(size_t)(l * 64 + lane) * 68 + 4 * (t ^ rots)];
#pragma unroll
        for (int j = 0; j < EB; ++j)
          r4[j][l] += xq[j].x * w.x + xq[j].y * w.y + xq[j].z * w.z +
                      xq[j].w * w.w;
      }
    }
    // accumulate messages: acc[lm] += Y[lm] * hs * R[l_of_lm]
#pragma unroll
    for (int j = 0; j < EB; ++j) {
      if (j < m) {  // wave-uniform
        const float* yp = sy + j * 16;
        float t0 = hs[j] * r4[j][0], t1 = hs[j] * r4[j][1];
        float t2 = hs[j] * r4[j][2], t3 = hs[j] * r4[j][3];
        acc[0] += yp[0] * t0;
        acc[1] += yp[1] * t1;   acc[2] += yp[2] * t1;   acc[3] += yp[3] * t1;
        acc[4] += yp[4] * t2;   acc[5] += yp[5] * t2;   acc[6] += yp[6] * t2;
        acc[7] += yp[7] * t2;   acc[8] += yp[8] * t2;
        acc[9] += yp[9] * t3;   acc[10] += yp[10] * t3; acc[11] += yp[11] * t3;
        acc[12] += yp[12] * t3; acc[13] += yp[13] * t3; acc[14] += yp[14] * t3;
      }
    }
    LDSFENCE();
  }

  // node update: inv = A0 + sum_lm A^2   (A = acc / 16)
  float inv = acc[0] * 0.0625f;
#pragma unroll
  for (int i = 0; i < 16; ++i) {
    float a2 = acc[i] * 0.0625f;
    inv += a2 * a2;
  }
  sv[lane] = inv;
  LDSFENCE();
  int sp = spec[n];
  const float* wsc = Wsc + ((size_t)layer * NE + sp) * 64 * 64;
  const float* wp = Wp + (size_t)layer * 64 * 64;
  const float* hold = h_in + (size_t)n * 64;
  float hv = 0.f;
#pragma unroll 4
  for (int k = 0; k < 64; ++k) {
    hv += sv[k] * wp[k * 64 + lane];
    hv += hold[k] * wsc[k * 64 + lane];
  }
  h_out[(size_t)n * 64 + lane] = hv;
  LDSFENCE();
  sv[lane] = hv;
  LDSFENCE();
  if (lane < 3) {
    const float* wr = Wread + (size_t)layer * 64 * 3;
    float s = 0.f;
#pragma unroll 8
    for (int d = 0; d < 64; ++d) s += sv[d] * wr[d * 3 + lane];
    atomicAdd(&energy[batch[n] * 3 + lane], s);
  }
}

// ---------------------------------------------------------------- output
__global__ void write_out_k(const float* __restrict__ energy,
                            float* __restrict__ out, int n) {
  int i = threadIdx.x;
  if (i < n) out[i] = energy[i];
}

// ---------------------------------------------------------------- host
extern "C" void kernel_launch(void* const* d_in, const int* in_sizes, int n_in,
                              void* d_out, int out_size, void* d_ws,
                              size_t ws_size, hipStream_t stream) {
  const float* pos = (const float*)d_in[0];
  const float* shifts = (const float*)d_in[1];
  const float* attrs = (const float*)d_in[2];
  const float* ae = (const float*)d_in[3];
  const float* Wemb = (const float*)d_in[4];
  const float* Wr1 = (const float*)d_in[5];
  const float* Wr2 = (const float*)d_in[6];
  const float* Wr3 = (const float*)d_in[7];
  const float* Wr4 = (const float*)d_in[8];
  const float* Wsc = (const float*)d_in[9];
  const float* Wp = (const float*)d_in[10];
  const float* Wrd = (const float*)d_in[11];
  const int* ei = (const int*)d_in[12];
  const int* batch = (const int*)d_in[13];

  int N = in_sizes[0] / 3;
  int E = in_sizes[12] / 2;
  int NE = in_sizes[3];
  int nlayer = in_sizes[5] / (8 * 64);

  char* w = (char*)d_ws;
  auto alloc = [&](size_t bytes) {
    void* p = (void*)w;
    w += (bytes + 255) & ~(size_t)255;
    return p;
  };
  float* h0 = (float*)alloc((size_t)N * 64 * 4);
  float* h1 = (float*)alloc((size_t)N * 64 * 4);
  float* Yc = (float*)alloc((size_t)E * 16 * 4);
  float* fc = (float*)alloc((size_t)E * 8 * 4);
  int* send = (int*)alloc((size_t)E * 4);
  int* off = (int*)alloc((size_t)(N + 1) * 4);
  int* deg = (int*)alloc((size_t)N * 4);
  int* cur = (int*)alloc((size_t)N * 4);
  int* spec = (int*)alloc((size_t)N * 4);
  float* energy = (float*)alloc(64 * 4);

  hipMemsetAsync(deg, 0, (size_t)N * 4, stream);
  hipMemsetAsync(cur, 0, (size_t)N * 4, stream);
  hipMemsetAsync(energy, 0, 64 * 4, stream);

  node_init_k<<<(N + 3) / 4, 256, 0, stream>>>(attrs, ae, Wemb, batch, h0, spec,
                                               energy, N, NE);
  edge_count_k<<<(E + 255) / 256, 256, 0, stream>>>(pos, shifts, ei, deg, E);
  scan_deg_k<<<1, 256, 0, stream>>>(deg, off, N);
  edge_fill_k<<<(E + 255) / 256, 256, 0, stream>>>(pos, shifts, ei, off, cur,
                                                   send, Yc, fc, E);
  float* hin = h0;
  float* hout = h1;
  for (int l = 0; l < nlayer; ++l) {
    gather_update_k<<<(N + NW - 1) / NW, 512, 0, stream>>>(
        hin, hout, Wr1, Wr2, Wr3, Wr4, Wsc, Wp, Wrd, Yc, fc, send, off, spec,
        batch, energy, N, NE, l);
    float* t = hin;
    hin = hout;
    hout = t;
  }
  write_out_k<<<1, 64, 0, stream>>>(energy, (float*)d_out, out_size);
}